// Round 1
// baseline (48148.535 us; speedup 1.0000x reference)
//
#include <hip/hip_runtime.h>
#include <math.h>

#define BB 64
#define TT 512
#define OBSN 64
#define EE 256
#define HH 4
#define HDN 64
#define MEMN 16
#define MACRO 10
#define FF 1024
#define NT 512

typedef unsigned short u16;
typedef u16 us4 __attribute__((ext_vector_type(4)));
typedef u16 us8 __attribute__((ext_vector_type(8)));

// bf16 workspace layout (element offsets)
#define OFF_Wi 0
#define OFF_Wq 16384
#define OFF_Wk 81920
#define OFF_Wv 147456
#define OFF_Wo 212992
#define OFF_W1 278528
#define OFF_W2 540672
#define OFF_Wa 802816
#define OFF_XO 1064960
#define CONV_N 1064960

__device__ inline float bf2f(u16 h) {
  union { unsigned u; float f; } x; x.u = ((unsigned)h) << 16; return x.f;
}
__device__ inline u16 f2bf(float f) {
  union { float f; unsigned u; } x; x.f = f;
  unsigned u = x.u;
  return (u16)((u + 0x7fffu + ((u >> 16) & 1u)) >> 16);
}
__device__ inline float gelu_f(float x) {
  float x3 = x * x * x;
  float u = 0.7978845608028654f * (x + 0.044715f * x3);
  return 0.5f * x * (1.0f + tanhf(u));
}

__global__ __launch_bounds__(256) void convert_kernel(
    const float* __restrict__ Wi, const float* __restrict__ Wq, const float* __restrict__ Wk,
    const float* __restrict__ Wv, const float* __restrict__ Wo, const float* __restrict__ W1,
    const float* __restrict__ W2, const float* __restrict__ Wa, u16* __restrict__ ws) {
  for (int i = blockIdx.x * blockDim.x + threadIdx.x; i < CONV_N; i += gridDim.x * blockDim.x) {
    const float* s; int off;
    if (i < OFF_Wq)      { s = Wi; off = i; }
    else if (i < OFF_Wk) { s = Wq; off = i - OFF_Wq; }
    else if (i < OFF_Wv) { s = Wk; off = i - OFF_Wk; }
    else if (i < OFF_Wo) { s = Wv; off = i - OFF_Wv; }
    else if (i < OFF_W1) { s = Wo; off = i - OFF_Wo; }
    else if (i < OFF_W2) { s = W1; off = i - OFF_W1; }
    else if (i < OFF_Wa) { s = W2; off = i - OFF_W2; }
    else                 { s = Wa; off = i - OFF_Wa; }
    ws[i] = f2bf(s[off]);
  }
}

// Sliced matvec: out[N] = in[K] @ W[K][N] (bf16 weights, [in][out] layout, coalesced
// row reads). 512 threads = (N/8) column-groups x S row-slices; partials to LDS.
template <int K, int N>
__device__ inline void mv_partial(const u16* __restrict__ W, const float* __restrict__ in,
                                  float* __restrict__ part, int tid) {
  constexpr int NG = N / 8;
  constexpr int S  = NT / NG;
  constexpr int KS = K / S;
  const int g = tid & (NG - 1);
  const int s = tid / NG;
  float acc[8] = {0.f, 0.f, 0.f, 0.f, 0.f, 0.f, 0.f, 0.f};
  const u16* wp = W + (size_t)s * KS * N + (size_t)g * 8;
  const float* ip = in + s * KS;
#pragma unroll 16
  for (int e = 0; e < KS; ++e) {
    float xe = ip[e];
    us8 w = *(const us8*)(wp + (size_t)e * N);
#pragma unroll
    for (int j = 0; j < 8; ++j) acc[j] += xe * bf2f((u16)w[j]);
  }
  float* pp = part + s * N + g * 8;
#pragma unroll
  for (int j = 0; j < 8; ++j) pp[j] = acc[j];
}

__device__ inline void block_ln(const float* __restrict__ vin, const float* __restrict__ sc,
                                const float* __restrict__ sh, float* __restrict__ vout,
                                float* __restrict__ red, int tid) {
  float x = 0.f;
  if (tid < EE) x = vin[tid];
  float s1 = x, s2 = x * x;
#pragma unroll
  for (int o = 32; o >= 1; o >>= 1) {
    s1 += __shfl_xor(s1, o, 64);
    s2 += __shfl_xor(s2, o, 64);
  }
  const int wid = tid >> 6, lane = tid & 63;
  if (tid < EE && lane == 0) { red[wid] = s1; red[8 + wid] = s2; }
  __syncthreads();
  if (tid == 0) {
    float S1 = red[0] + red[1] + red[2] + red[3];
    float S2 = red[8] + red[9] + red[10] + red[11];
    float m = S1 * (1.f / EE);
    float var = S2 * (1.f / EE) - m * m;
    red[0] = m;
    red[1] = rsqrtf(var + 1e-6f);
  }
  __syncthreads();
  if (tid < EE) vout[tid] = (x - red[0]) * red[1] * sc[tid] + sh[tid];
  __syncthreads();
}

__global__ __launch_bounds__(NT) void scan_kernel(
    const float* __restrict__ obs, const unsigned char* __restrict__ freeze,
    const float* __restrict__ bi, const float* __restrict__ temb,
    const float* __restrict__ alpha, const float* __restrict__ lam,
    const float* __restrict__ ln1s, const float* __restrict__ ln1b,
    const float* __restrict__ bq, const float* __restrict__ bk,
    const float* __restrict__ bv, const float* __restrict__ bo,
    const float* __restrict__ ln2s, const float* __restrict__ ln2b,
    const float* __restrict__ b1, const float* __restrict__ b2,
    const u16* __restrict__ wsw, u16* __restrict__ xout) {
  __shared__ float s_xin[EE], s_y[EE], s_q[EE], s_ctx[EE], s_xmid[EE], s_z[EE];
  __shared__ float s_g[FF];
  __shared__ float s_kc[MEMN * EE], s_vc[MEMN * EE];
  __shared__ float s_part[4096];
  __shared__ float s_obs[OBSN];
  __shared__ float s_sc[HH * MEMN], s_attn[HH * MEMN];
  __shared__ float s_ssum[EE];
  __shared__ float s_a[EE], s_l[EE];
  __shared__ float s_p1s[EE], s_p1b[EE], s_p2s[EE], s_p2b[EE];
  __shared__ float s_bi[EE], s_bq[EE], s_bk[EE], s_bv[EE], s_bo[EE], s_b2[EE];
  __shared__ float s_b1[FF];
  __shared__ float s_temb[(MACRO + 1) * EE];
  __shared__ float s_red[16];

  const int b = blockIdx.x;
  const int tid = threadIdx.x;

  for (int i = tid; i < EE; i += NT) {
    s_bi[i] = bi[i];
    s_a[i] = 1.f / (1.f + expf(-alpha[i]));
    s_l[i] = 1.f / (1.f + expf(-lam[i]));
    s_p1s[i] = ln1s[i]; s_p1b[i] = ln1b[i];
    s_p2s[i] = ln2s[i]; s_p2b[i] = ln2b[i];
    s_bq[i] = bq[i]; s_bk[i] = bk[i]; s_bv[i] = bv[i]; s_bo[i] = bo[i];
    s_b2[i] = b2[i];
    s_ssum[i] = 0.f;
  }
  for (int i = tid; i < FF; i += NT) s_b1[i] = b1[i];
  for (int i = tid; i < (MACRO + 1) * EE; i += NT) s_temb[i] = temb[i];
  // empty memory slots: k = bk, v = bv (zero-vector @ W + bias)
  for (int i = tid; i < MEMN * EE; i += NT) {
    s_kc[i] = bk[i & (EE - 1)];
    s_vc[i] = bv[i & (EE - 1)];
  }
  __syncthreads();

  const u16* Wi = wsw + OFF_Wi;
  const u16* Wq = wsw + OFF_Wq;
  const u16* Wk = wsw + OFF_Wk;
  const u16* Wv = wsw + OFF_Wv;
  const u16* Wo = wsw + OFF_Wo;
  const u16* W1 = wsw + OFF_W1;
  const u16* W2 = wsw + OFF_W2;

  for (int t = 0; t < TT; ++t) {
    if (tid < OBSN) s_obs[tid] = obs[((size_t)b * TT + t) * OBSN + tid];
    __syncthreads();

    // x_in = obs @ Wi + bi + temb[t % MACRO] + ssum * a
    mv_partial<OBSN, EE>(Wi, s_obs, s_part, tid);
    __syncthreads();
    {
      const float* te = s_temb + (t % MACRO) * EE;
      for (int c = tid; c < EE; c += NT) {
        float v = 0.f;
#pragma unroll
        for (int s2 = 0; s2 < 16; ++s2) v += s_part[s2 * EE + c];
        s_xin[c] = v + s_bi[c] + te[c] + s_ssum[c] * s_a[c];
      }
    }
    __syncthreads();

    block_ln(s_xin, s_p1s, s_p1b, s_y, s_red, tid);

    // q = (ln1(x_in) @ Wq + bq) * 1/sqrt(HD)
    mv_partial<EE, EE>(Wq, s_y, s_part, tid);
    __syncthreads();
    for (int c = tid; c < EE; c += NT) {
      float v = 0.f;
#pragma unroll
      for (int s2 = 0; s2 < 16; ++s2) v += s_part[s2 * EE + c];
      s_q[c] = (v + s_bq[c]) * 0.125f;
    }
    __syncthreads();

    // k_t, v_t into ring slot t%16 (mem entry is x_in pre-LN)
    const int slot = t & (MEMN - 1);
    mv_partial<EE, EE>(Wk, s_xin, s_part, tid);
    __syncthreads();
    for (int c = tid; c < EE; c += NT) {
      float v = 0.f;
#pragma unroll
      for (int s2 = 0; s2 < 16; ++s2) v += s_part[s2 * EE + c];
      s_kc[slot * EE + c] = v + s_bk[c];
    }
    __syncthreads();
    mv_partial<EE, EE>(Wv, s_xin, s_part, tid);
    __syncthreads();
    for (int c = tid; c < EE; c += NT) {
      float v = 0.f;
#pragma unroll
      for (int s2 = 0; s2 < 16; ++s2) v += s_part[s2 * EE + c];
      s_vc[slot * EE + c] = v + s_bv[c];
    }
    __syncthreads();

    // scores: mem index m corresponds to time t-15+m -> ring slot (t+1+m)&15
    if (tid < HH * MEMN) {
      int h = tid >> 4, m = tid & (MEMN - 1);
      int sl = (t + 1 + m) & (MEMN - 1);
      const float* kp = s_kc + sl * EE + h * HDN;
      const float* qp = s_q + h * HDN;
      float sum = 0.f;
#pragma unroll 16
      for (int d = 0; d < HDN; ++d) sum += qp[d] * kp[d];
      s_sc[tid] = sum;
    }
    __syncthreads();
    if (tid < HH) {
      float mx = -1e30f;
      for (int m = 0; m < MEMN; ++m) mx = fmaxf(mx, s_sc[tid * MEMN + m]);
      float sm = 0.f;
      float ex[MEMN];
      for (int m = 0; m < MEMN; ++m) { ex[m] = expf(s_sc[tid * MEMN + m] - mx); sm += ex[m]; }
      float inv = 1.f / sm;
      for (int m = 0; m < MEMN; ++m) s_attn[tid * MEMN + m] = ex[m] * inv;
    }
    __syncthreads();
    if (tid < EE) {
      int h = tid >> 6;
      float sum = 0.f;
#pragma unroll
      for (int m = 0; m < MEMN; ++m) {
        int sl = (t + 1 + m) & (MEMN - 1);
        sum += s_attn[h * MEMN + m] * s_vc[sl * EE + tid];
      }
      s_ctx[tid] = sum;
    }
    __syncthreads();

    // out projection; x_mid = x_in + (ctx @ Wo + bo)
    mv_partial<EE, EE>(Wo, s_ctx, s_part, tid);
    __syncthreads();
    for (int c = tid; c < EE; c += NT) {
      float v = 0.f;
#pragma unroll
      for (int s2 = 0; s2 < 16; ++s2) v += s_part[s2 * EE + c];
      s_xmid[c] = s_xin[c] + v + s_bo[c];
    }
    __syncthreads();

    block_ln(s_xmid, s_p2s, s_p2b, s_z, s_red, tid);

    // FFN1 + gelu
    mv_partial<EE, FF>(W1, s_z, s_part, tid);
    __syncthreads();
    for (int c = tid; c < FF; c += NT) {
      float v = 0.f;
#pragma unroll
      for (int s2 = 0; s2 < 4; ++s2) v += s_part[s2 * FF + c];
      s_g[c] = gelu_f(v + s_b1[c]);
    }
    __syncthreads();

    // FFN2; x_out; ssum update; store x_out (bf16)
    mv_partial<FF, EE>(W2, s_g, s_part, tid);
    __syncthreads();
    {
      const unsigned char frz = freeze[b * TT + t];
      for (int c = tid; c < EE; c += NT) {
        float v = 0.f;
#pragma unroll
        for (int s2 = 0; s2 < 16; ++s2) v += s_part[s2 * EE + c];
        float xo = s_xmid[c] + v + s_b2[c];
        float lc = s_l[c];
        float ns = s_ssum[c] * lc + xo * (1.f - lc);
        if (!frz) s_ssum[c] = ns;
        xout[((size_t)b * TT + t) * EE + c] = f2bf(xo);
      }
    }
    __syncthreads();
  }
}

// logits = xout(32768x256) @ Wa(256x1024) + ba, fp32 out. 64x64 tiles, 256 threads.
__global__ __launch_bounds__(256) void logits_kernel(
    const u16* __restrict__ xo, const u16* __restrict__ Wa,
    const float* __restrict__ ba, float* __restrict__ out) {
  __shared__ float As[64][68];
  __shared__ float Bs[64][68];
  const int r0 = blockIdx.x * 64;
  const int c0 = blockIdx.y * 64;
  const int tid = threadIdx.x;
  const int tx = tid & 15, ty = tid >> 4;
  float acc[4][4] = {};
  for (int k0 = 0; k0 < EE; k0 += 64) {
    __syncthreads();
    for (int l = tid * 4; l < 4096; l += 1024) {
      int rr = l >> 6, cc = l & 63;
      us4 av = *(const us4*)(xo + ((size_t)(r0 + rr)) * EE + k0 + cc);
      us4 wv = *(const us4*)(Wa + ((size_t)(k0 + rr)) * 1024 + c0 + cc);
#pragma unroll
      for (int j = 0; j < 4; ++j) {
        As[rr][cc + j] = bf2f((u16)av[j]);
        Bs[rr][cc + j] = bf2f((u16)wv[j]);
      }
    }
    __syncthreads();
#pragma unroll 8
    for (int kk = 0; kk < 64; ++kk) {
      float a4[4], b4[4];
#pragma unroll
      for (int i = 0; i < 4; ++i) a4[i] = As[ty * 4 + i][kk];
#pragma unroll
      for (int j = 0; j < 4; ++j) b4[j] = Bs[kk][tx * 4 + j];
#pragma unroll
      for (int i = 0; i < 4; ++i)
#pragma unroll
        for (int j = 0; j < 4; ++j) acc[i][j] += a4[i] * b4[j];
    }
  }
  float bav[4];
#pragma unroll
  for (int j = 0; j < 4; ++j) bav[j] = ba[c0 + tx * 4 + j];
#pragma unroll
  for (int i = 0; i < 4; ++i) {
    float4 v;
    v.x = acc[i][0] + bav[0];
    v.y = acc[i][1] + bav[1];
    v.z = acc[i][2] + bav[2];
    v.w = acc[i][3] + bav[3];
    *(float4*)(out + ((size_t)(r0 + ty * 4 + i)) * 1024 + c0 + tx * 4) = v;
  }
}

extern "C" void kernel_launch(void* const* d_in, const int* in_sizes, int n_in,
                              void* d_out, int out_size, void* d_ws, size_t ws_size,
                              hipStream_t stream) {
  const float* obs  = (const float*)d_in[0];
  const unsigned char* freeze = (const unsigned char*)d_in[1];
  const float* Wi   = (const float*)d_in[2];
  const float* bi   = (const float*)d_in[3];
  const float* temb = (const float*)d_in[4];
  const float* alpha = (const float*)d_in[5];
  const float* lam  = (const float*)d_in[6];
  const float* ln1s = (const float*)d_in[7];
  const float* ln1b = (const float*)d_in[8];
  const float* Wq   = (const float*)d_in[9];
  const float* bq   = (const float*)d_in[10];
  const float* Wk   = (const float*)d_in[11];
  const float* bk   = (const float*)d_in[12];
  const float* Wv   = (const float*)d_in[13];
  const float* bv   = (const float*)d_in[14];
  const float* Wo   = (const float*)d_in[15];
  const float* bo   = (const float*)d_in[16];
  const float* ln2s = (const float*)d_in[17];
  const float* ln2b = (const float*)d_in[18];
  const float* W1   = (const float*)d_in[19];
  const float* b1   = (const float*)d_in[20];
  const float* W2   = (const float*)d_in[21];
  const float* b2   = (const float*)d_in[22];
  const float* Wa   = (const float*)d_in[23];
  const float* ba   = (const float*)d_in[24];
  u16* ws = (u16*)d_ws;

  hipLaunchKernelGGL(convert_kernel, dim3((CONV_N + 255) / 256), dim3(256), 0, stream,
                     Wi, Wq, Wk, Wv, Wo, W1, W2, Wa, ws);
  hipLaunchKernelGGL(scan_kernel, dim3(BB), dim3(NT), 0, stream,
                     obs, freeze, bi, temb, alpha, lam, ln1s, ln1b,
                     bq, bk, bv, bo, ln2s, ln2b, b1, b2, ws, ws + OFF_XO);
  hipLaunchKernelGGL(logits_kernel, dim3(BB * TT / 64, 1024 / 64), dim3(256), 0, stream,
                     ws + OFF_XO, ws + OFF_Wa, ba, (float*)d_out);
}

// Round 2
// 41199.741 us; speedup vs baseline: 1.1687x; 1.1687x over previous
//
#include <hip/hip_runtime.h>
#include <math.h>

#define BB 64
#define TT 512
#define OBSN 64
#define EE 256
#define HH 4
#define HDN 64
#define MEMN 16
#define MACRO 10
#define FF 1024
#define NT 1024

typedef unsigned short u16;
typedef u16 us4 __attribute__((ext_vector_type(4)));
typedef u16 us8 __attribute__((ext_vector_type(8)));

// bf16 workspace layout (element offsets). KV = Wk|Wv interleaved as [256][512]
#define OFF_Wi 0
#define OFF_Wq 16384
#define OFF_KV 81920
#define OFF_Wo 212992
#define OFF_W1 278528
#define OFF_W2 540672
#define OFF_Wa 802816
#define OFF_XO 1064960
#define CONV_N 1064960

__device__ inline float bf2f(u16 h) {
  union { unsigned u; float f; } x; x.u = ((unsigned)h) << 16; return x.f;
}
__device__ inline u16 f2bf(float f) {
  union { float f; unsigned u; } x; x.f = f;
  unsigned u = x.u;
  return (u16)((u + 0x7fffu + ((u >> 16) & 1u)) >> 16);
}
__device__ inline float gelu_f(float x) {
  float x3 = x * x * x;
  float u = 0.7978845608028654f * (x + 0.044715f * x3);
  return 0.5f * x * (1.0f + tanhf(u));
}

__global__ __launch_bounds__(256) void convert_kernel(
    const float* __restrict__ Wi, const float* __restrict__ Wq, const float* __restrict__ Wk,
    const float* __restrict__ Wv, const float* __restrict__ Wo, const float* __restrict__ W1,
    const float* __restrict__ W2, const float* __restrict__ Wa, u16* __restrict__ ws) {
  for (int i = blockIdx.x * blockDim.x + threadIdx.x; i < CONV_N; i += gridDim.x * blockDim.x) {
    float val;
    if (i < OFF_Wq)      val = Wi[i];
    else if (i < OFF_KV) val = Wq[i - OFF_Wq];
    else if (i < OFF_Wo) {
      int off = i - OFF_KV; int row = off >> 9; int col = off & 511;
      val = (col < 256) ? Wk[row * 256 + col] : Wv[row * 256 + (col - 256)];
    }
    else if (i < OFF_W1) val = Wo[i - OFF_Wo];
    else if (i < OFF_W2) val = W1[i - OFF_W1];
    else if (i < OFF_Wa) val = W2[i - OFF_W2];
    else                 val = Wa[i - OFF_Wa];
    ws[i] = f2bf(val);
  }
}

// Issue async global->LDS copy of 32 KB (16384 bf16). 1024 threads x 2 x 16B.
// LDS dest must be wave-uniform base; lane offset (lane*16B) is implicit HW behavior.
__device__ __forceinline__ void stage32k(const u16* __restrict__ gsrc, u16* lbuf, int tid) {
  const int wid = tid >> 6;
  __builtin_amdgcn_global_load_lds(
      (const __attribute__((address_space(1))) unsigned int*)(gsrc + (size_t)tid * 8),
      (__attribute__((address_space(3))) unsigned int*)(lbuf + wid * 512),
      16, 0, 0);
  __builtin_amdgcn_global_load_lds(
      (const __attribute__((address_space(1))) unsigned int*)(gsrc + 8192 + (size_t)tid * 8),
      (__attribute__((address_space(3))) unsigned int*)(lbuf + 8192 + wid * 512),
      16, 0, 0);
}

// Staged matvec: part[s*N + g*8 ..] = partial sums of out[N] = in[K] @ W[K][N].
// W streamed through 2x32KB LDS ring via global_load_lds; each thread owns 8 output
// cols (group g) and 2 rows per chunk (slice s); acc persists across chunks.
template <int K, int N>
__device__ __forceinline__ void mv_stage(const u16* __restrict__ Wg,
                                         const float* __restrict__ in,
                                         u16 (*wb)[16384], float* __restrict__ part,
                                         int tid) {
  constexpr int NG = N / 8;             // column groups
  constexpr int NCH = (K * N) / 16384;  // 32KB chunks
  constexpr int RCH = 16384 / N;        // rows per chunk
  const int g = tid & (NG - 1);
  const int s = tid / NG;               // slice (0 .. 8192/N - 1)
  float acc[8] = {0.f, 0.f, 0.f, 0.f, 0.f, 0.f, 0.f, 0.f};
  stage32k(Wg, wb[0], tid);
  asm volatile("s_waitcnt vmcnt(0)" ::: "memory");
  __syncthreads();
  int cur = 0;
  for (int c = 0; c < NCH; ++c) {
    if (c + 1 < NCH) stage32k(Wg + (size_t)(c + 1) * 16384, wb[cur ^ 1], tid);
    const u16* wl = wb[cur];
    const float* ip = in + c * RCH;
#pragma unroll
    for (int rr = 0; rr < 2; ++rr) {
      const int r = s * 2 + rr;
      const float xe = ip[r];
      const us8 w = *(const us8*)(wl + r * N + g * 8);
#pragma unroll
      for (int j = 0; j < 8; ++j) acc[j] += xe * bf2f((u16)w[j]);
    }
    asm volatile("s_waitcnt vmcnt(0)" ::: "memory");
    __syncthreads();
    cur ^= 1;
  }
  float* pp = part + s * N + g * 8;
#pragma unroll
  for (int j = 0; j < 8; ++j) pp[j] = acc[j];
  __syncthreads();
}

__device__ inline void block_ln(const float* __restrict__ vin, const float* __restrict__ sc,
                                const float* __restrict__ sh, float* __restrict__ vout,
                                float* __restrict__ red, int tid) {
  float x = 0.f;
  if (tid < EE) x = vin[tid];
  float s1 = x, s2 = x * x;
#pragma unroll
  for (int o = 32; o >= 1; o >>= 1) {
    s1 += __shfl_xor(s1, o, 64);
    s2 += __shfl_xor(s2, o, 64);
  }
  const int wid = tid >> 6, lane = tid & 63;
  if (tid < EE && lane == 0) { red[wid] = s1; red[8 + wid] = s2; }
  __syncthreads();
  if (tid == 0) {
    float S1 = red[0] + red[1] + red[2] + red[3];
    float S2 = red[8] + red[9] + red[10] + red[11];
    float m = S1 * (1.f / EE);
    float var = S2 * (1.f / EE) - m * m;
    red[0] = m;
    red[1] = rsqrtf(var + 1e-6f);
  }
  __syncthreads();
  if (tid < EE) vout[tid] = (x - red[0]) * red[1] * sc[tid] + sh[tid];
  __syncthreads();
}

__global__ __launch_bounds__(NT) void scan_kernel(
    const float* __restrict__ obs, const unsigned char* __restrict__ freeze,
    const float* __restrict__ bi, const float* __restrict__ temb,
    const float* __restrict__ alpha, const float* __restrict__ lam,
    const float* __restrict__ ln1s, const float* __restrict__ ln1b,
    const float* __restrict__ bq, const float* __restrict__ bk,
    const float* __restrict__ bv, const float* __restrict__ bo,
    const float* __restrict__ ln2s, const float* __restrict__ ln2b,
    const float* __restrict__ b1, const float* __restrict__ b2,
    const u16* __restrict__ wsw, u16* __restrict__ xout) {
  __shared__ u16 s_wb[2][16384];        // 64 KB weight ring
  __shared__ float s_part[8192];        // 32 KB partial sums
  __shared__ float s_kc[MEMN * EE];     // 16 KB k cache
  __shared__ float s_vc[MEMN * EE];     // 16 KB v cache
  __shared__ float s_gel[FF];           // 4 KB
  __shared__ float s_b1[FF];            // 4 KB
  __shared__ float s_act[7 * EE];       // xin,y,q,ctx,xmid,z,ssum
  __shared__ float s_prm[12 * EE];      // bi,a,l,1s,1b,2s,2b,bq,bk,bv,bo,b2
  __shared__ float s_misc[208];         // obs(64) sc(64) attn(64) red(16)

  float* s_xin  = s_act;
  float* s_y    = s_act + 256;
  float* s_q    = s_act + 512;
  float* s_ctx  = s_act + 768;
  float* s_xmid = s_act + 1024;
  float* s_z    = s_act + 1280;
  float* s_ssum = s_act + 1536;
  float* P_bi = s_prm;         float* P_a  = s_prm + 256;  float* P_l  = s_prm + 512;
  float* P_1s = s_prm + 768;   float* P_1b = s_prm + 1024;
  float* P_2s = s_prm + 1280;  float* P_2b = s_prm + 1536;
  float* P_bq = s_prm + 1792;  float* P_bk = s_prm + 2048; float* P_bv = s_prm + 2304;
  float* P_bo = s_prm + 2560;  float* P_b2 = s_prm + 2816;
  float* s_obs  = s_misc;
  float* s_sc   = s_misc + 64;
  float* s_attn = s_misc + 128;
  float* s_red  = s_misc + 192;

  const int b = blockIdx.x;
  const int tid = threadIdx.x;

  for (int i = tid; i < EE; i += NT) {
    P_bi[i] = bi[i];
    P_a[i] = 1.f / (1.f + expf(-alpha[i]));
    P_l[i] = 1.f / (1.f + expf(-lam[i]));
    P_1s[i] = ln1s[i]; P_1b[i] = ln1b[i];
    P_2s[i] = ln2s[i]; P_2b[i] = ln2b[i];
    P_bq[i] = bq[i]; P_bk[i] = bk[i]; P_bv[i] = bv[i]; P_bo[i] = bo[i];
    P_b2[i] = b2[i];
    s_ssum[i] = 0.f;
  }
  for (int i = tid; i < FF; i += NT) s_b1[i] = b1[i];
  // empty memory slots: k = bk, v = bv (zero-vector @ W + bias)
  for (int i = tid; i < MEMN * EE; i += NT) {
    s_kc[i] = bk[i & (EE - 1)];
    s_vc[i] = bv[i & (EE - 1)];
  }
  __syncthreads();

  const u16* Wi  = wsw + OFF_Wi;
  const u16* Wq  = wsw + OFF_Wq;
  const u16* WKV = wsw + OFF_KV;
  const u16* Wo  = wsw + OFF_Wo;
  const u16* W1  = wsw + OFF_W1;
  const u16* W2  = wsw + OFF_W2;

  for (int t = 0; t < TT; ++t) {
    if (tid < OBSN) s_obs[tid] = obs[((size_t)b * TT + t) * OBSN + tid];
    // visibility of s_obs guaranteed by mv_stage's internal prefetch barrier

    // x_in = obs @ Wi + bi + temb[t % MACRO] + ssum * a
    mv_stage<OBSN, EE>(Wi, s_obs, s_wb, s_part, tid);
    if (tid < EE) {
      float v = 0.f;
#pragma unroll
      for (int s2 = 0; s2 < 32; ++s2) v += s_part[s2 * EE + tid];
      float te = temb[(t % MACRO) * EE + tid];
      s_xin[tid] = v + P_bi[tid] + te + s_ssum[tid] * P_a[tid];
    }
    __syncthreads();

    block_ln(s_xin, P_1s, P_1b, s_y, s_red, tid);

    // q = (ln1(x_in) @ Wq + bq) / sqrt(HD)
    mv_stage<EE, EE>(Wq, s_y, s_wb, s_part, tid);
    if (tid < EE) {
      float v = 0.f;
#pragma unroll
      for (int s2 = 0; s2 < 32; ++s2) v += s_part[s2 * EE + tid];
      s_q[tid] = (v + P_bq[tid]) * 0.125f;
    }
    // k,v fused: [256][512] interleaved weight matrix, input x_in
    mv_stage<EE, 2 * EE>(WKV, s_xin, s_wb, s_part, tid);
    const int slot = t & (MEMN - 1);
    if (tid < 2 * EE) {
      float v = 0.f;
#pragma unroll
      for (int s2 = 0; s2 < 16; ++s2) v += s_part[s2 * 512 + tid];
      if (tid < EE) s_kc[slot * EE + tid] = v + P_bk[tid];
      else          s_vc[slot * EE + (tid - EE)] = v + P_bv[tid - EE];
    }
    __syncthreads();

    // scores: mem index m -> time t-15+m -> ring slot (t+1+m)&15
    if (tid < HH * MEMN) {
      int h = tid >> 4, m = tid & (MEMN - 1);
      int sl = (t + 1 + m) & (MEMN - 1);
      const float* kp = s_kc + sl * EE + h * HDN;
      const float* qp = s_q + h * HDN;
      float sum = 0.f;
#pragma unroll 16
      for (int d = 0; d < HDN; ++d) sum += qp[d] * kp[d];
      s_sc[tid] = sum;
    }
    __syncthreads();
    if (tid < HH) {
      float mx = -1e30f;
      for (int m = 0; m < MEMN; ++m) mx = fmaxf(mx, s_sc[tid * MEMN + m]);
      float sm = 0.f;
      float ex[MEMN];
      for (int m = 0; m < MEMN; ++m) { ex[m] = expf(s_sc[tid * MEMN + m] - mx); sm += ex[m]; }
      float inv = 1.f / sm;
      for (int m = 0; m < MEMN; ++m) s_attn[tid * MEMN + m] = ex[m] * inv;
    }
    __syncthreads();
    if (tid < EE) {
      int h = tid >> 6;
      float sum = 0.f;
#pragma unroll
      for (int m = 0; m < MEMN; ++m) {
        int sl = (t + 1 + m) & (MEMN - 1);
        sum += s_attn[h * MEMN + m] * s_vc[sl * EE + tid];
      }
      s_ctx[tid] = sum;
    }
    // visibility via mv_stage internal barrier

    // x_mid = x_in + ctx @ Wo + bo
    mv_stage<EE, EE>(Wo, s_ctx, s_wb, s_part, tid);
    if (tid < EE) {
      float v = 0.f;
#pragma unroll
      for (int s2 = 0; s2 < 32; ++s2) v += s_part[s2 * EE + tid];
      s_xmid[tid] = s_xin[tid] + v + P_bo[tid];
    }
    __syncthreads();

    block_ln(s_xmid, P_2s, P_2b, s_z, s_red, tid);

    // FFN1 + gelu
    mv_stage<EE, FF>(W1, s_z, s_wb, s_part, tid);
    {
      float v = 0.f;
#pragma unroll
      for (int s2 = 0; s2 < 8; ++s2) v += s_part[s2 * FF + tid];
      s_gel[tid] = gelu_f(v + s_b1[tid]);
    }
    // visibility via mv_stage internal barrier

    // FFN2; x_out; ssum update; store bf16
    mv_stage<FF, EE>(W2, s_gel, s_wb, s_part, tid);
    {
      const unsigned char frz = freeze[b * TT + t];
      if (tid < EE) {
        float v = 0.f;
#pragma unroll
        for (int s2 = 0; s2 < 32; ++s2) v += s_part[s2 * EE + tid];
        float xo = s_xmid[tid] + v + P_b2[tid];
        float lc = P_l[tid];
        float ns = s_ssum[tid] * lc + xo * (1.f - lc);
        if (!frz) s_ssum[tid] = ns;
        xout[((size_t)b * TT + t) * EE + tid] = f2bf(xo);
      }
    }
    __syncthreads();
  }
}

// logits = xout(32768x256) @ Wa(256x1024) + ba, fp32 out. 64x64 tiles, 256 threads.
// A staged transposed -> both operands read as ds_read_b128 rows.
__global__ __launch_bounds__(256) void logits_kernel(
    const u16* __restrict__ xo, const u16* __restrict__ Wa,
    const float* __restrict__ ba, float* __restrict__ out) {
  __shared__ float AsT[64][68];  // [k][row]
  __shared__ float Bs[64][68];   // [k][col]
  const int r0 = blockIdx.x * 64;
  const int c0 = blockIdx.y * 64;
  const int tid = threadIdx.x;
  const int tx = tid & 15, ty = tid >> 4;
  float acc[4][4] = {};
  for (int k0 = 0; k0 < EE; k0 += 64) {
    __syncthreads();
    for (int l = tid * 4; l < 4096; l += 1024) {
      int rr = l >> 6, cc = l & 63;
      us4 av = *(const us4*)(xo + ((size_t)(r0 + rr)) * EE + k0 + cc);
      us4 wv = *(const us4*)(Wa + ((size_t)(k0 + rr)) * 1024 + c0 + cc);
#pragma unroll
      for (int j = 0; j < 4; ++j) {
        AsT[cc + j][rr] = bf2f((u16)av[j]);   // transpose A
        Bs[rr][cc + j] = bf2f((u16)wv[j]);
      }
    }
    __syncthreads();
#pragma unroll 4
    for (int kk = 0; kk < 64; ++kk) {
      float4 a4 = *(const float4*)&AsT[kk][ty * 4];
      float4 b4 = *(const float4*)&Bs[kk][tx * 4];
      float av_[4] = {a4.x, a4.y, a4.z, a4.w};
      float bv_[4] = {b4.x, b4.y, b4.z, b4.w};
#pragma unroll
      for (int i = 0; i < 4; ++i)
#pragma unroll
        for (int j = 0; j < 4; ++j) acc[i][j] += av_[i] * bv_[j];
    }
  }
  float bav[4];
#pragma unroll
  for (int j = 0; j < 4; ++j) bav[j] = ba[c0 + tx * 4 + j];
#pragma unroll
  for (int i = 0; i < 4; ++i) {
    float4 v;
    v.x = acc[i][0] + bav[0];
    v.y = acc[i][1] + bav[1];
    v.z = acc[i][2] + bav[2];
    v.w = acc[i][3] + bav[3];
    *(float4*)(out + ((size_t)(r0 + ty * 4 + i)) * 1024 + c0 + tx * 4) = v;
  }
}

extern "C" void kernel_launch(void* const* d_in, const int* in_sizes, int n_in,
                              void* d_out, int out_size, void* d_ws, size_t ws_size,
                              hipStream_t stream) {
  const float* obs  = (const float*)d_in[0];
  const unsigned char* freeze = (const unsigned char*)d_in[1];
  const float* Wi   = (const float*)d_in[2];
  const float* bi   = (const float*)d_in[3];
  const float* temb = (const float*)d_in[4];
  const float* alpha = (const float*)d_in[5];
  const float* lam  = (const float*)d_in[6];
  const float* ln1s = (const float*)d_in[7];
  const float* ln1b = (const float*)d_in[8];
  const float* Wq   = (const float*)d_in[9];
  const float* bq   = (const float*)d_in[10];
  const float* Wk   = (const float*)d_in[11];
  const float* bk   = (const float*)d_in[12];
  const float* Wv   = (const float*)d_in[13];
  const float* bv   = (const float*)d_in[14];
  const float* Wo   = (const float*)d_in[15];
  const float* bo   = (const float*)d_in[16];
  const float* ln2s = (const float*)d_in[17];
  const float* ln2b = (const float*)d_in[18];
  const float* W1   = (const float*)d_in[19];
  const float* b1   = (const float*)d_in[20];
  const float* W2   = (const float*)d_in[21];
  const float* b2   = (const float*)d_in[22];
  const float* Wa   = (const float*)d_in[23];
  const float* ba   = (const float*)d_in[24];
  u16* ws = (u16*)d_ws;

  hipLaunchKernelGGL(convert_kernel, dim3((CONV_N + 255) / 256), dim3(256), 0, stream,
                     Wi, Wq, Wk, Wv, Wo, W1, W2, Wa, ws);
  hipLaunchKernelGGL(scan_kernel, dim3(BB), dim3(NT), 0, stream,
                     obs, freeze, bi, temb, alpha, lam, ln1s, ln1b,
                     bq, bk, bv, bo, ln2s, ln2b, b1, b2, ws, ws + OFF_XO);
  hipLaunchKernelGGL(logits_kernel, dim3(BB * TT / 64, 1024 / 64), dim3(256), 0, stream,
                     ws + OFF_XO, ws + OFF_Wa, ba, (float*)d_out);
}

// Round 3
// 23920.006 us; speedup vs baseline: 2.0129x; 1.7224x over previous
//
#include <hip/hip_runtime.h>
#include <math.h>

#define BB 64
#define TT 512
#define OBSN 64
#define EE 256
#define HH 4
#define MEMN 16
#define MACRO 10
#define FF 1024
#define NT 1024

typedef unsigned short u16;
typedef unsigned int u32;
typedef u16 us4 __attribute__((ext_vector_type(4)));
typedef _Float16 h2 __attribute__((ext_vector_type(2)));

// f16 pair-word (u32) offsets: word(k2,n) = (W[2k2][n], W[2k2+1][n])
#define PW_Wi 0
#define PW_Wq 8192
#define PW_Wk 40960
#define PW_Wv 73728
#define PW_Wo 106496
#define PW_W1 139264
#define PW_W2 270336
#define PW_TOTAL 401408
// u16-element offsets in ws
#define OFF_Wa 802816   // Wa plain f16 [256][1024]
#define OFF_XO 1064960  // xout f16 (B*T*E)
#define WA_N 262144

__device__ __forceinline__ u32 pack2(float a, float b) {
  union { _Float16 h; u16 s; } ca, cb;
  ca.h = (_Float16)a; cb.h = (_Float16)b;
  return (u32)ca.s | ((u32)cb.s << 16);
}
__device__ __forceinline__ float h2f(u16 s) {
  union { u16 s; _Float16 h; } c; c.s = s; return (float)c.h;
}
__device__ __forceinline__ u16 f2h(float f) {
  union { _Float16 h; u16 s; } c; c.h = (_Float16)f; return c.s;
}
__device__ __forceinline__ float dot2(u32 x, u32 w, float c) {
#if __has_builtin(__builtin_amdgcn_fdot2)
  return __builtin_amdgcn_fdot2(__builtin_bit_cast(h2, x), __builtin_bit_cast(h2, w), c, false);
#else
  union { u32 u; _Float16 h[2]; } a, b; a.u = x; b.u = w;
  return c + (float)a.h[0] * (float)b.h[0] + (float)a.h[1] * (float)b.h[1];
#endif
}
__device__ __forceinline__ float gelu_f(float x) {
  float x3 = x * x * x;
  float u = 0.7978845608028654f * (x + 0.044715f * x3);
  return 0.5f * x * (1.0f + tanhf(u));
}

// Repack fp32 weights -> f16 pair-words (+ Wa as plain f16)
__global__ __launch_bounds__(256) void convert_kernel(
    const float* __restrict__ Wi, const float* __restrict__ Wq, const float* __restrict__ Wk,
    const float* __restrict__ Wv, const float* __restrict__ Wo, const float* __restrict__ W1,
    const float* __restrict__ W2, const float* __restrict__ Wa, u16* __restrict__ ws) {
  u32* ws32 = (u32*)ws;
  const int total = PW_TOTAL + WA_N;
  for (int i = blockIdx.x * blockDim.x + threadIdx.x; i < total; i += gridDim.x * blockDim.x) {
    if (i < PW_TOTAL) {
      const float* src; int off; int n1024 = 0;
      if (i < PW_Wq)      { src = Wi; off = i; }
      else if (i < PW_Wk) { src = Wq; off = i - PW_Wq; }
      else if (i < PW_Wv) { src = Wk; off = i - PW_Wk; }
      else if (i < PW_Wo) { src = Wv; off = i - PW_Wv; }
      else if (i < PW_W1) { src = Wo; off = i - PW_Wo; }
      else if (i < PW_W2) { src = W1; off = i - PW_W1; n1024 = 1; }
      else                { src = W2; off = i - PW_W2; }
      int k2, n;
      if (n1024) { k2 = off >> 10; n = off & 1023; }
      else       { k2 = off >> 8;  n = off & 255; }
      int N = n1024 ? 1024 : 256;
      float a = src[(2 * k2) * N + n];
      float b = src[(2 * k2 + 1) * N + n];
      ws32[i] = pack2(a, b);
    } else {
      int j = i - PW_TOTAL;
      ws[OFF_Wa + j] = f2h(Wa[j]);
    }
  }
}

// One GEMV stage: thread (s,g) holds W[k2-slice][n-cols] in regs (f16 pairs),
// reads x-pairs from LDS (wave-uniform -> broadcast), writes partials to LDS.
template <int S, int G, int CN, int CK2, int N, int WRDS>
__device__ __forceinline__ void stage_dot(const u32 (&w)[WRDS], const u32* __restrict__ x16,
                                          float* __restrict__ part, int tid) {
  const int g = tid & (G - 1);
  const int s = tid / G;
  u32 xp[CK2];
#pragma unroll
  for (int j = 0; j < CK2; ++j) xp[j] = x16[s * CK2 + j];
  float acc[CN];
#pragma unroll
  for (int n = 0; n < CN; ++n) acc[n] = 0.f;
#pragma unroll
  for (int j = 0; j < CK2; ++j)
#pragma unroll
    for (int n = 0; n < CN; ++n) acc[n] = dot2(xp[j], w[j * CN + n], acc[n]);
  float* pp = part + s * N + g * CN;
#pragma unroll
  for (int n = 0; n < CN; ++n) pp[n] = acc[n];
}

__global__ __launch_bounds__(NT) void scan_kernel(
    const float* __restrict__ obs, const unsigned char* __restrict__ freeze,
    const float* __restrict__ bi, const float* __restrict__ temb,
    const float* __restrict__ alpha, const float* __restrict__ lam,
    const float* __restrict__ ln1s, const float* __restrict__ ln1b,
    const float* __restrict__ bq, const float* __restrict__ bk,
    const float* __restrict__ bv, const float* __restrict__ bo,
    const float* __restrict__ ln2s, const float* __restrict__ ln2b,
    const float* __restrict__ b1, const float* __restrict__ b2,
    const u16* __restrict__ wsw, u16* __restrict__ xout) {
  __shared__ float s_part[12288];            // 48 KB (q|k|v regions; reused by all stages)
  __shared__ float s_kc[MEMN * EE];          // 16 KB
  __shared__ float s_vc[MEMN * EE];          // 16 KB
  __shared__ float s_xin[EE], s_q[EE], s_xmid[EE], s_ssum[EE];
  __shared__ u32 s_obs16[32], s_y16[128], s_xin16[128], s_ctx16[128], s_z16[128], s_gel16[512];
  __shared__ float s_prm[12 * EE];           // 12 KB params
  __shared__ float s_b1[FF];                 // 4 KB
  __shared__ float s_temb[(MACRO + 1) * EE]; // 11 KB
  __shared__ u32 s_frz[TT / 4];              // 512 B
  __shared__ float s_attn[HH * MEMN];
  __shared__ float s_red[16];

  float* P_bi = s_prm;        float* P_a  = s_prm + 256;  float* P_l  = s_prm + 512;
  float* P_1s = s_prm + 768;  float* P_1b = s_prm + 1024;
  float* P_2s = s_prm + 1280; float* P_2b = s_prm + 1536;
  float* P_bq = s_prm + 1792; float* P_bk = s_prm + 2048; float* P_bv = s_prm + 2304;
  float* P_bo = s_prm + 2560; float* P_b2 = s_prm + 2816;

  const int b = blockIdx.x;
  const int tid = threadIdx.x;

  // ---- resident weights: 392 u32 regs/thread of f16 pairs, static indexing only
  u32 wWi[8], wWq[32], wWk[32], wWv[32], wWo[32], wW1[128], wW2[128];
  const u32* W32 = (const u32*)wsw;
  {
    const int g = tid & 63, s = tid >> 6;
#pragma unroll
    for (int j = 0; j < 2; ++j) {
      uint4 q = *(const uint4*)(W32 + PW_Wi + (s * 2 + j) * 256 + g * 4);
      wWi[j * 4 + 0] = q.x; wWi[j * 4 + 1] = q.y; wWi[j * 4 + 2] = q.z; wWi[j * 4 + 3] = q.w;
    }
#pragma unroll
    for (int j = 0; j < 8; ++j) {
      uint4 q = *(const uint4*)(W32 + PW_Wq + (s * 8 + j) * 256 + g * 4);
      wWq[j * 4 + 0] = q.x; wWq[j * 4 + 1] = q.y; wWq[j * 4 + 2] = q.z; wWq[j * 4 + 3] = q.w;
    }
#pragma unroll
    for (int j = 0; j < 8; ++j) {
      uint4 q = *(const uint4*)(W32 + PW_Wk + (s * 8 + j) * 256 + g * 4);
      wWk[j * 4 + 0] = q.x; wWk[j * 4 + 1] = q.y; wWk[j * 4 + 2] = q.z; wWk[j * 4 + 3] = q.w;
    }
#pragma unroll
    for (int j = 0; j < 8; ++j) {
      uint4 q = *(const uint4*)(W32 + PW_Wv + (s * 8 + j) * 256 + g * 4);
      wWv[j * 4 + 0] = q.x; wWv[j * 4 + 1] = q.y; wWv[j * 4 + 2] = q.z; wWv[j * 4 + 3] = q.w;
    }
#pragma unroll
    for (int j = 0; j < 8; ++j) {
      uint4 q = *(const uint4*)(W32 + PW_Wo + (s * 8 + j) * 256 + g * 4);
      wWo[j * 4 + 0] = q.x; wWo[j * 4 + 1] = q.y; wWo[j * 4 + 2] = q.z; wWo[j * 4 + 3] = q.w;
    }
  }
  {
    const int g = tid & 127, s = tid >> 7;
#pragma unroll
    for (int j = 0; j < 16; ++j) {
      uint4 q0 = *(const uint4*)(W32 + PW_W1 + (s * 16 + j) * 1024 + g * 8);
      uint4 q1 = *(const uint4*)(W32 + PW_W1 + (s * 16 + j) * 1024 + g * 8 + 4);
      wW1[j * 8 + 0] = q0.x; wW1[j * 8 + 1] = q0.y; wW1[j * 8 + 2] = q0.z; wW1[j * 8 + 3] = q0.w;
      wW1[j * 8 + 4] = q1.x; wW1[j * 8 + 5] = q1.y; wW1[j * 8 + 6] = q1.z; wW1[j * 8 + 7] = q1.w;
    }
  }
  {
    const int g = tid & 31, s = tid >> 5;
#pragma unroll
    for (int j = 0; j < 16; ++j) {
      uint4 q0 = *(const uint4*)(W32 + PW_W2 + (s * 16 + j) * 256 + g * 8);
      uint4 q1 = *(const uint4*)(W32 + PW_W2 + (s * 16 + j) * 256 + g * 8 + 4);
      wW2[j * 8 + 0] = q0.x; wW2[j * 8 + 1] = q0.y; wW2[j * 8 + 2] = q0.z; wW2[j * 8 + 3] = q0.w;
      wW2[j * 8 + 4] = q1.x; wW2[j * 8 + 5] = q1.y; wW2[j * 8 + 6] = q1.z; wW2[j * 8 + 7] = q1.w;
    }
  }

  for (int i = tid; i < EE; i += NT) {
    P_bi[i] = bi[i];
    P_a[i] = 1.f / (1.f + expf(-alpha[i]));
    P_l[i] = 1.f / (1.f + expf(-lam[i]));
    P_1s[i] = ln1s[i]; P_1b[i] = ln1b[i];
    P_2s[i] = ln2s[i]; P_2b[i] = ln2b[i];
    P_bq[i] = bq[i]; P_bk[i] = bk[i]; P_bv[i] = bv[i]; P_bo[i] = bo[i];
    P_b2[i] = b2[i];
    s_ssum[i] = 0.f;
  }
  for (int i = tid; i < FF; i += NT) s_b1[i] = b1[i];
  for (int i = tid; i < (MACRO + 1) * EE; i += NT) s_temb[i] = temb[i];
  if (tid < TT / 4) s_frz[tid] = ((const u32*)(freeze + (size_t)b * TT))[tid];
  // empty mem slots: k = bk, v = bv (zero-vector @ W + bias)
  for (int i = tid; i < MEMN * EE; i += NT) {
    s_kc[i] = bk[i & (EE - 1)];
    s_vc[i] = bv[i & (EE - 1)];
  }
  __syncthreads();

  float4 obs_pf;
  if (tid < 16) obs_pf = *(const float4*)(obs + (size_t)b * TT * OBSN + tid * 4);

  for (int t = 0; t < TT; ++t) {
    if (tid < 16) {
      s_obs16[tid * 2]     = pack2(obs_pf.x, obs_pf.y);
      s_obs16[tid * 2 + 1] = pack2(obs_pf.z, obs_pf.w);
    }
    __syncthreads();

    // x_in = obs @ Wi + bi + temb + ssum*a
    stage_dot<16, 64, 4, 2, 256>(wWi, s_obs16, s_part, tid);
    if (tid < 16) {
      int tn = (t + 1 < TT) ? t + 1 : t;
      obs_pf = *(const float4*)(obs + ((size_t)b * TT + tn) * OBSN + tid * 4);
    }
    __syncthreads();
    {
      const int tmod = t % MACRO;
      if (tid < EE) {
        float v = 0.f;
#pragma unroll
        for (int s = 0; s < 16; ++s) v += s_part[s * 256 + tid];
        v += P_bi[tid] + s_temb[tmod * 256 + tid] + s_ssum[tid] * P_a[tid];
        s_xin[tid] = v;
        float vn = __shfl_xor(v, 1);
        if (!(tid & 1)) s_xin16[tid >> 1] = pack2(v, vn);
      }
    }
    __syncthreads();

    // LN1 -> y16
    {
      float x = (tid < EE) ? s_xin[tid] : 0.f;
      float s1 = x, s2 = x * x;
#pragma unroll
      for (int o = 32; o >= 1; o >>= 1) { s1 += __shfl_xor(s1, o, 64); s2 += __shfl_xor(s2, o, 64); }
      if (tid < EE && (tid & 63) == 0) { s_red[tid >> 6] = s1; s_red[8 + (tid >> 6)] = s2; }
      __syncthreads();
      if (tid < EE) {
        float S1 = s_red[0] + s_red[1] + s_red[2] + s_red[3];
        float S2 = s_red[8] + s_red[9] + s_red[10] + s_red[11];
        float m = S1 * (1.f / EE);
        float rs = rsqrtf(S2 * (1.f / EE) - m * m + 1e-6f);
        float v = (x - m) * rs * P_1s[tid] + P_1b[tid];
        float vn = __shfl_xor(v, 1);
        if (!(tid & 1)) s_y16[tid >> 1] = pack2(v, vn);
      }
      __syncthreads();
    }

    // q|k|v in one phase (three part regions)
    stage_dot<16, 64, 4, 8, 256>(wWq, s_y16, s_part, tid);
    stage_dot<16, 64, 4, 8, 256>(wWk, s_xin16, s_part + 4096, tid);
    stage_dot<16, 64, 4, 8, 256>(wWv, s_xin16, s_part + 8192, tid);
    __syncthreads();
    const int slot = t & (MEMN - 1);
    if (tid < 768) {
      int r = tid >> 8, c = tid & 255;
      float v = 0.f;
#pragma unroll
      for (int s = 0; s < 16; ++s) v += s_part[r * 4096 + s * 256 + c];
      if (r == 0)      s_q[c] = (v + P_bq[c]) * 0.125f;
      else if (r == 1) s_kc[slot * 256 + c] = v + P_bk[c];
      else             s_vc[slot * 256 + c] = v + P_bv[c];
    }
    __syncthreads();

    // scores + softmax (wave 0; 16-lane groups per head)
    if (tid < 64) {
      int h = tid >> 4, m = tid & 15, sl = (t + 1 + m) & 15;
      const float* kp = s_kc + sl * 256 + h * 64;
      const float* qp = s_q + h * 64;
      float sc = 0.f;
#pragma unroll
      for (int d = 0; d < 64; ++d) sc += qp[d] * kp[d];
      float mx = sc;
#pragma unroll
      for (int o = 8; o >= 1; o >>= 1) mx = fmaxf(mx, __shfl_xor(mx, o, 16));
      float ex = expf(sc - mx), sm = ex;
#pragma unroll
      for (int o = 8; o >= 1; o >>= 1) sm += __shfl_xor(sm, o, 16);
      s_attn[tid] = ex / sm;
    }
    __syncthreads();
    if (tid < EE) {
      int h = tid >> 6;
      float sum = 0.f;
#pragma unroll
      for (int m = 0; m < 16; ++m) {
        int sl = (t + 1 + m) & 15;
        sum += s_attn[h * 16 + m] * s_vc[sl * 256 + tid];
      }
      float vn = __shfl_xor(sum, 1);
      if (!(tid & 1)) s_ctx16[tid >> 1] = pack2(sum, vn);
    }
    __syncthreads();

    // x_mid = x_in + ctx @ Wo + bo
    stage_dot<16, 64, 4, 8, 256>(wWo, s_ctx16, s_part, tid);
    __syncthreads();
    if (tid < EE) {
      float v = 0.f;
#pragma unroll
      for (int s = 0; s < 16; ++s) v += s_part[s * 256 + tid];
      s_xmid[tid] = s_xin[tid] + v + P_bo[tid];
    }
    __syncthreads();

    // LN2 -> z16
    {
      float x = (tid < EE) ? s_xmid[tid] : 0.f;
      float s1 = x, s2 = x * x;
#pragma unroll
      for (int o = 32; o >= 1; o >>= 1) { s1 += __shfl_xor(s1, o, 64); s2 += __shfl_xor(s2, o, 64); }
      if (tid < EE && (tid & 63) == 0) { s_red[tid >> 6] = s1; s_red[8 + (tid >> 6)] = s2; }
      __syncthreads();
      if (tid < EE) {
        float S1 = s_red[0] + s_red[1] + s_red[2] + s_red[3];
        float S2 = s_red[8] + s_red[9] + s_red[10] + s_red[11];
        float m = S1 * (1.f / EE);
        float rs = rsqrtf(S2 * (1.f / EE) - m * m + 1e-6f);
        float v = (x - m) * rs * P_2s[tid] + P_2b[tid];
        float vn = __shfl_xor(v, 1);
        if (!(tid & 1)) s_z16[tid >> 1] = pack2(v, vn);
      }
      __syncthreads();
    }

    // FFN1 + gelu
    stage_dot<8, 128, 8, 16, 1024>(wW1, s_z16, s_part, tid);
    __syncthreads();
    {
      float v = 0.f;
#pragma unroll
      for (int s = 0; s < 8; ++s) v += s_part[s * 1024 + tid];
      v += s_b1[tid];
      float gl = gelu_f(v);
      float vn = __shfl_xor(gl, 1);
      if (!(tid & 1)) s_gel16[tid >> 1] = pack2(gl, vn);
    }
    __syncthreads();

    // FFN2; x_out; ssum; store
    stage_dot<32, 32, 8, 16, 256>(wW2, s_gel16, s_part, tid);
    __syncthreads();
    {
      const int frz = (s_frz[t >> 2] >> ((t & 3) * 8)) & 0xff;
      if (tid < EE) {
        float v = 0.f;
#pragma unroll
        for (int s = 0; s < 32; ++s) v += s_part[s * 256 + tid];
        float xo = s_xmid[tid] + v + P_b2[tid];
        float lc = P_l[tid];
        if (!frz) s_ssum[tid] = s_ssum[tid] * lc + xo * (1.f - lc);
        xout[((size_t)b * TT + t) * EE + tid] = f2h(xo);
      }
    }
    __syncthreads();
  }
}

// logits = xout(32768x256 f16) @ Wa(256x1024 f16) + ba, fp32 out
__global__ __launch_bounds__(256) void logits_kernel(
    const u16* __restrict__ xo, const u16* __restrict__ Wa,
    const float* __restrict__ ba, float* __restrict__ out) {
  __shared__ float AsT[64][68];  // [k][row]
  __shared__ float Bs[64][68];   // [k][col]
  const int r0 = blockIdx.x * 64;
  const int c0 = blockIdx.y * 64;
  const int tid = threadIdx.x;
  const int tx = tid & 15, ty = tid >> 4;
  float acc[4][4] = {};
  for (int k0 = 0; k0 < EE; k0 += 64) {
    __syncthreads();
    for (int l = tid * 4; l < 4096; l += 1024) {
      int rr = l >> 6, cc = l & 63;
      us4 av = *(const us4*)(xo + ((size_t)(r0 + rr)) * EE + k0 + cc);
      us4 wv = *(const us4*)(Wa + ((size_t)(k0 + rr)) * 1024 + c0 + cc);
#pragma unroll
      for (int j = 0; j < 4; ++j) {
        AsT[cc + j][rr] = h2f((u16)av[j]);
        Bs[rr][cc + j] = h2f((u16)wv[j]);
      }
    }
    __syncthreads();
#pragma unroll 4
    for (int kk = 0; kk < 64; ++kk) {
      float4 a4 = *(const float4*)&AsT[kk][ty * 4];
      float4 b4 = *(const float4*)&Bs[kk][tx * 4];
      float av_[4] = {a4.x, a4.y, a4.z, a4.w};
      float bv_[4] = {b4.x, b4.y, b4.z, b4.w};
#pragma unroll
      for (int i = 0; i < 4; ++i)
#pragma unroll
        for (int j = 0; j < 4; ++j) acc[i][j] += av_[i] * bv_[j];
    }
  }
  float bav[4];
#pragma unroll
  for (int j = 0; j < 4; ++j) bav[j] = ba[c0 + tx * 4 + j];
#pragma unroll
  for (int i = 0; i < 4; ++i) {
    float4 v;
    v.x = acc[i][0] + bav[0];
    v.y = acc[i][1] + bav[1];
    v.z = acc[i][2] + bav[2];
    v.w = acc[i][3] + bav[3];
    *(float4*)(out + ((size_t)(r0 + ty * 4 + i)) * 1024 + c0 + tx * 4) = v;
  }
}

extern "C" void kernel_launch(void* const* d_in, const int* in_sizes, int n_in,
                              void* d_out, int out_size, void* d_ws, size_t ws_size,
                              hipStream_t stream) {
  const float* obs  = (const float*)d_in[0];
  const unsigned char* freeze = (const unsigned char*)d_in[1];
  const float* Wi   = (const float*)d_in[2];
  const float* bi   = (const float*)d_in[3];
  const float* temb = (const float*)d_in[4];
  const float* alpha = (const float*)d_in[5];
  const float* lam  = (const float*)d_in[6];
  const float* ln1s = (const float*)d_in[7];
  const float* ln1b = (const float*)d_in[8];
  const float* Wq   = (const float*)d_in[9];
  const float* bq   = (const float*)d_in[10];
  const float* Wk   = (const float*)d_in[11];
  const float* bk   = (const float*)d_in[12];
  const float* Wv   = (const float*)d_in[13];
  const float* bv   = (const float*)d_in[14];
  const float* Wo   = (const float*)d_in[15];
  const float* bo   = (const float*)d_in[16];
  const float* ln2s = (const float*)d_in[17];
  const float* ln2b = (const float*)d_in[18];
  const float* W1   = (const float*)d_in[19];
  const float* b1   = (const float*)d_in[20];
  const float* W2   = (const float*)d_in[21];
  const float* b2   = (const float*)d_in[22];
  const float* Wa   = (const float*)d_in[23];
  const float* ba   = (const float*)d_in[24];
  u16* ws = (u16*)d_ws;

  hipLaunchKernelGGL(convert_kernel, dim3(1296), dim3(256), 0, stream,
                     Wi, Wq, Wk, Wv, Wo, W1, W2, Wa, ws);
  hipLaunchKernelGGL(scan_kernel, dim3(BB), dim3(NT), 0, stream,
                     obs, freeze, bi, temb, alpha, lam, ln1s, ln1b,
                     bq, bk, bv, bo, ln2s, ln2b, b1, b2, ws, ws + OFF_XO);
  hipLaunchKernelGGL(logits_kernel, dim3(BB * TT / 64, 1024 / 64), dim3(256), 0, stream,
                     ws + OFF_XO, ws + OFF_Wa, ba, (float*)d_out);
}

// Round 5
// 11323.687 us; speedup vs baseline: 4.2520x; 2.1124x over previous
//
#include <hip/hip_runtime.h>
#include <math.h>

#define BB 64
#define TT 512
#define EE 256
#define MACRO 10
#define NT 512

typedef unsigned short u16;
typedef unsigned int u32;
typedef u16 us4 __attribute__((ext_vector_type(4)));
typedef _Float16 h2 __attribute__((ext_vector_type(2)));

// ---- ws layout in u32 words ----
// 4 weight shards (one per head/member), packed:
//   per shard: Wq[128][64] | Wk | Wv | Wo[32][256] | W1[128][256] | W2[128][256]
#define SH_STRIDE 98304
#define SH_WK 8192
#define SH_WV 16384
#define SH_WO 24576
#define SH_W1 32768
#define SH_W2 65536
#define W_WI  393216   // Wi pairs [32][256] = 8192 words (replicated use)
#define W_WA  401408   // Wa f16 pairs, 131072 words
#define W_PY  532480   // partial_y  [64][4][256] f32
#define W_PXO 598016   // partial_xo [64][4][256] f32
#define W_SEQ 663552   // seqy[256] | seqx[256]
#define W_XO  664064   // xout f16 pairs, 4194304 words
#define CONV_TOTAL 664064

__device__ __forceinline__ u32 pack2(float a, float b) {
  union { _Float16 h; u16 s; } ca, cb;
  ca.h = (_Float16)a; cb.h = (_Float16)b;
  return (u32)ca.s | ((u32)cb.s << 16);
}
__device__ __forceinline__ float h2f(u16 s) {
  union { u16 s; _Float16 h; } c; c.s = s; return (float)c.h;
}
__device__ __forceinline__ float dot2(u32 x, u32 w, float c) {
#if __has_builtin(__builtin_amdgcn_fdot2)
  return __builtin_amdgcn_fdot2(__builtin_bit_cast(h2, x), __builtin_bit_cast(h2, w), c, false);
#else
  union { u32 u; _Float16 h[2]; } a, b; a.u = x; b.u = w;
  return c + (float)a.h[0] * (float)b.h[0] + (float)a.h[1] * (float)b.h[1];
#endif
}
__device__ __forceinline__ float gelu_f(float x) {
  float x3 = x * x * x;
  float u = 0.7978845608028654f * (x + 0.044715f * x3);
  return 0.5f * x * (1.0f + tanhf(u));
}

__global__ __launch_bounds__(256) void convert_kernel(
    const float* __restrict__ Wi, const float* __restrict__ Wq, const float* __restrict__ Wk,
    const float* __restrict__ Wv, const float* __restrict__ Wo, const float* __restrict__ W1,
    const float* __restrict__ W2, const float* __restrict__ Wa, u16* __restrict__ ws) {
  u32* ws32 = (u32*)ws;
  for (int i = blockIdx.x * blockDim.x + threadIdx.x; i < CONV_TOTAL;
       i += gridDim.x * blockDim.x) {
    if (i < 393216) {
      int j = i / SH_STRIDE, off = i - j * SH_STRIDE;
      float a, b;
      if (off < SH_WO) {
        int which = off >> 13, r = off & 8191, k2 = r >> 6, n = r & 63;
        const float* W = which == 0 ? Wq : (which == 1 ? Wk : Wv);
        a = W[(2 * k2) * 256 + j * 64 + n];
        b = W[(2 * k2 + 1) * 256 + j * 64 + n];
      } else if (off < SH_W1) {
        int r = off - SH_WO, k2 = r >> 8, n = r & 255;
        a = Wo[j * 16384 + (2 * k2) * 256 + n];
        b = Wo[j * 16384 + (2 * k2 + 1) * 256 + n];
      } else if (off < SH_W2) {
        int r = off - SH_W1, k2 = r >> 8, n = r & 255;
        a = W1[(2 * k2) * 1024 + j * 256 + n];
        b = W1[(2 * k2 + 1) * 1024 + j * 256 + n];
      } else {
        int r = off - SH_W2, k2 = r >> 8, n = r & 255;
        a = W2[(j * 256 + 2 * k2) * 256 + n];
        b = W2[(j * 256 + 2 * k2 + 1) * 256 + n];
      }
      ws32[i] = pack2(a, b);
    } else if (i < W_WA) {
      int w = i - W_WI, k2 = w >> 8, n = w & 255;
      ws32[i] = pack2(Wi[(2 * k2) * 256 + n], Wi[(2 * k2 + 1) * 256 + n]);
    } else if (i < W_PY) {
      int w = i - W_WA;
      ws32[i] = pack2(Wa[2 * w], Wa[2 * w + 1]);
    } else {
      ws32[i] = 0;  // zero partials + seq counters
    }
  }
}

// reg-weight matvec: thread (s,g) owns CK2 k2-words x CN cols; partials to LDS
template <int G, int CN, int CK2, int N>
__device__ __forceinline__ void mvr(const u32* __restrict__ w, const u32* __restrict__ x16,
                                    float* __restrict__ part, int tid) {
  const int g = tid & (G - 1);
  const int s = tid / G;
  float acc[CN];
#pragma unroll
  for (int n = 0; n < CN; ++n) acc[n] = 0.f;
#pragma unroll
  for (int jj = 0; jj < CK2; ++jj) {
    u32 xp = x16[s * CK2 + jj];
#pragma unroll
    for (int n = 0; n < CN; ++n) acc[n] = dot2(xp, w[jj * CN + n], acc[n]);
  }
  float* pp = part + s * N + g * CN;
#pragma unroll
  for (int n = 0; n < CN; ++n) pp[n] = acc[n];
}

__global__ __launch_bounds__(NT) void scan_kernel(
    const float* __restrict__ obs, const unsigned char* __restrict__ freeze,
    const float* __restrict__ bi, const float* __restrict__ temb,
    const float* __restrict__ alpha, const float* __restrict__ lam,
    const float* __restrict__ ln1s, const float* __restrict__ ln1b,
    const float* __restrict__ bq, const float* __restrict__ bk,
    const float* __restrict__ bv, const float* __restrict__ bo,
    const float* __restrict__ ln2s, const float* __restrict__ ln2b,
    const float* __restrict__ b1, const float* __restrict__ b2,
    u16* __restrict__ wsw) {
  __shared__ u32  s_w2[16384];         // 64 KB: W2 rows j2=8..15
  __shared__ float s_part[3072];       // 12 KB partials
  __shared__ float s_kc[64 * 16];      // k cache [d][slot]
  __shared__ float s_vc[16 * 64];      // v cache [slot][d]
  __shared__ float s_temb[MACRO * EE]; // 10 KB
  __shared__ u32  s_xin16[128], s_y16[128], s_z16[128], s_h16[128];
  __shared__ u32  s_ctx16[32], s_obs16[32];
  __shared__ float s_q[64], s_attn[16], s_red[16];
  __shared__ u32  s_frz[TT / 4];

  const int blk = blockIdx.x;
  const int b = blk & 63;
  const int j = blk >> 6;  // member = head = shard (likely co-XCD with partners)
  const int tid = threadIdx.x;
  u32* W32 = (u32*)wsw;
  const u32* shard = W32 + j * SH_STRIDE;
  float* py  = (float*)(W32 + W_PY);
  float* pxo = (float*)(W32 + W_PXO);
  int* seqy = (int*)(W32 + W_SEQ);
  int* seqx = seqy + 256;
  u32* xog = W32 + W_XO;

  // ---- resident weights in registers (f16 pair-words, static indexing) ----
  u32 wWi[16], wQ[16], wK[16], wV[16], wWo[16], wW1[64], wW2r[32];
  {
    const int g = tid & 63, s = tid >> 6;
#pragma unroll
    for (int i = 0; i < 16; ++i)
      wWi[i] = W32[W_WI + (s * 4 + (i >> 2)) * 256 + g * 4 + (i & 3)];
#pragma unroll
    for (int i = 0; i < 16; ++i)
      wWo[i] = shard[SH_WO + (s * 4 + (i >> 2)) * 256 + g * 4 + (i & 3)];
#pragma unroll
    for (int i = 0; i < 64; ++i)
      wW1[i] = shard[SH_W1 + (s * 16 + (i >> 2)) * 256 + g * 4 + (i & 3)];
#pragma unroll
    for (int i = 0; i < 32; ++i)
      wW2r[i] = shard[SH_W2 + (s * 16 + (i >> 2)) * 256 + g * 4 + (i & 3)];
  }
  {
    const int g = tid & 31, s = tid >> 5;
#pragma unroll
    for (int i = 0; i < 16; ++i) {
      wQ[i] = shard[(s * 8 + (i >> 1)) * 64 + g * 2 + (i & 1)];
      wK[i] = shard[SH_WK + (s * 8 + (i >> 1)) * 64 + g * 2 + (i & 1)];
      wV[i] = shard[SH_WV + (s * 8 + (i >> 1)) * 64 + g * 2 + (i & 1)];
    }
  }
  // W2 rows 8..15 of each slice -> LDS
  for (int i = tid; i < 16384; i += NT)
    s_w2[i] = shard[SH_W2 + ((i >> 11) * 16 + 8 + ((i >> 8) & 7)) * 256 + (i & 255)];

  // ---- per-thread params ----
  float bi_r = 0, a_r = 0, l_r = 0, p1s_r = 0, p1b_r = 0, p2s_r = 0, p2b_r = 0;
  float bo_r = 0, b1_r = 0, b2_r = 0, bqkv_r = 0, ssum_r = 0;
  if (tid < 256) {
    bi_r = bi[tid];
    a_r = 1.f / (1.f + expf(-alpha[tid]));
    l_r = 1.f / (1.f + expf(-lam[tid]));
    p1s_r = ln1s[tid]; p1b_r = ln1b[tid];
    p2s_r = ln2s[tid]; p2b_r = ln2b[tid];
    b1_r = b1[j * 256 + tid]; b2_r = b2[tid];
    if (j == 0) bo_r = bo[tid];
  }
  if (tid < 192) {
    int r = tid >> 6, c = tid & 63;
    bqkv_r = (r == 0 ? bq : (r == 1 ? bk : bv))[j * 64 + c];
  }
  for (int i = tid; i < MACRO * EE; i += NT) s_temb[i] = temb[i];
  if (tid < TT / 4) s_frz[tid] = ((const u32*)(freeze + (size_t)b * TT))[tid];
  // empty mem: k = bk, v = bv
  for (int i = tid; i < 1024; i += NT) {
    s_kc[i] = bk[j * 64 + (i >> 4)];
    s_vc[i] = bv[j * 64 + (i & 63)];
  }
  float4 obs_pf = make_float4(0.f, 0.f, 0.f, 0.f);
  if (tid < 16) obs_pf = *(const float4*)(obs + (size_t)b * TT * 64 + tid * 4);
  __syncthreads();

  for (int t = 0; t < TT; ++t) {
    const int tmod = t % MACRO;
    const int slot = t & 15;
    if (tid < 16) {
      s_obs16[tid * 2]     = pack2(obs_pf.x, obs_pf.y);
      s_obs16[tid * 2 + 1] = pack2(obs_pf.z, obs_pf.w);
    }
    __syncthreads();

    // x_in = obs @ Wi + bi + temb + ssum*a   (Wi replicated: identical on all members)
    mvr<64, 4, 4, 256>(wWi, s_obs16, s_part, tid);
    if (tid < 16) {
      int tn = (t + 1 < TT) ? t + 1 : t;
      obs_pf = *(const float4*)(obs + ((size_t)b * TT + tn) * 64 + tid * 4);
    }
    __syncthreads();
    float xin_r = 0.f;
    {
      float x = 0.f;
      if (tid < 256) {
        float v = 0.f;
#pragma unroll
        for (int s = 0; s < 8; ++s) v += s_part[s * 256 + tid];
        xin_r = v + bi_r + s_temb[tmod * 256 + tid] + ssum_r * a_r;
        float vn = __shfl_xor(xin_r, 1);
        if (!(tid & 1)) s_xin16[tid >> 1] = pack2(xin_r, vn);
        x = xin_r;
      }
      // LN1 -> y16
      float s1 = x, s2 = x * x;
#pragma unroll
      for (int o = 32; o >= 1; o >>= 1) { s1 += __shfl_xor(s1, o, 64); s2 += __shfl_xor(s2, o, 64); }
      if (tid < 256 && (tid & 63) == 0) { s_red[tid >> 6] = s1; s_red[8 + (tid >> 6)] = s2; }
      __syncthreads();
      if (tid < 256) {
        float S1 = s_red[0] + s_red[1] + s_red[2] + s_red[3];
        float S2 = s_red[8] + s_red[9] + s_red[10] + s_red[11];
        float m = S1 * (1.f / 256), rs = rsqrtf(S2 * (1.f / 256) - m * m + 1e-6f);
        float v = (x - m) * rs * p1s_r + p1b_r;
        float vn = __shfl_xor(v, 1);
        if (!(tid & 1)) s_y16[tid >> 1] = pack2(v, vn);
      }
    }
    __syncthreads();

    // q/k/v (head j only)
    mvr<32, 2, 8, 64>(wQ, s_y16,   s_part,        tid);
    mvr<32, 2, 8, 64>(wK, s_xin16, s_part + 1024, tid);
    mvr<32, 2, 8, 64>(wV, s_xin16, s_part + 2048, tid);
    __syncthreads();
    if (tid < 192) {
      int r = tid >> 6, c = tid & 63;
      float v = 0.f;
#pragma unroll
      for (int s = 0; s < 16; ++s) v += s_part[r * 1024 + s * 64 + c];
      v += bqkv_r;
      if (r == 0)      s_q[c] = v * 0.125f;
      else if (r == 1) s_kc[c * 16 + slot] = v;
      else             s_vc[slot * 64 + c] = v;
    }
    __syncthreads();

    // attention (local head): scores -> softmax -> ctx
    if (tid < 16) {
      int sl = (t + 1 + tid) & 15;
      float sc = 0.f;
#pragma unroll
      for (int d = 0; d < 64; ++d) sc += s_q[d] * s_kc[d * 16 + sl];
      float mx = sc;
#pragma unroll
      for (int o = 8; o >= 1; o >>= 1) mx = fmaxf(mx, __shfl_xor(mx, o, 16));
      float ex = expf(sc - mx), sm = ex;
#pragma unroll
      for (int o = 8; o >= 1; o >>= 1) sm += __shfl_xor(sm, o, 16);
      s_attn[tid] = ex / sm;
    }
    __syncthreads();
    if (tid < 64) {
      float sum = 0.f;
#pragma unroll
      for (int m = 0; m < 16; ++m) {
        int sl = (t + 1 + m) & 15;
        sum += s_attn[m] * s_vc[sl * 64 + tid];
      }
      float vn = __shfl_xor(sum, 1);
      if (!(tid & 1)) s_ctx16[tid >> 1] = pack2(sum, vn);
    }
    __syncthreads();

    // y partial = ctx_j @ Wo[j] (+bo on j0) -> post & all-reduce
    mvr<64, 4, 4, 256>(wWo, s_ctx16, s_part, tid);
    __syncthreads();
    if (tid < 256) {
      float v = 0.f;
#pragma unroll
      for (int s = 0; s < 8; ++s) v += s_part[s * 256 + tid];
      if (j == 0) v += bo_r;
      __hip_atomic_store(&py[(b * 4 + j) * 256 + tid], v, __ATOMIC_RELAXED, __HIP_MEMORY_SCOPE_AGENT);
    }
    __syncthreads();
    if (tid == 0) {
      __threadfence();
      __hip_atomic_store(&seqy[b * 4 + j], t + 1, __ATOMIC_RELEASE, __HIP_MEMORY_SCOPE_AGENT);
    }
    if (tid < 4) {
      while (__hip_atomic_load(&seqy[b * 4 + tid], __ATOMIC_ACQUIRE, __HIP_MEMORY_SCOPE_AGENT) < t + 1)
        __builtin_amdgcn_s_sleep(1);
    }
    __syncthreads();
    float xm_r = 0.f;
    {
      float x = 0.f;
      if (tid < 256) {
        float y0 = __hip_atomic_load(&py[(b * 4 + 0) * 256 + tid], __ATOMIC_RELAXED, __HIP_MEMORY_SCOPE_AGENT);
        float y1 = __hip_atomic_load(&py[(b * 4 + 1) * 256 + tid], __ATOMIC_RELAXED, __HIP_MEMORY_SCOPE_AGENT);
        float y2 = __hip_atomic_load(&py[(b * 4 + 2) * 256 + tid], __ATOMIC_RELAXED, __HIP_MEMORY_SCOPE_AGENT);
        float y3 = __hip_atomic_load(&py[(b * 4 + 3) * 256 + tid], __ATOMIC_RELAXED, __HIP_MEMORY_SCOPE_AGENT);
        xm_r = xin_r + ((y0 + y1) + (y2 + y3));
        x = xm_r;
      }
      // LN2 -> z16
      float s1 = x, s2 = x * x;
#pragma unroll
      for (int o = 32; o >= 1; o >>= 1) { s1 += __shfl_xor(s1, o, 64); s2 += __shfl_xor(s2, o, 64); }
      if (tid < 256 && (tid & 63) == 0) { s_red[tid >> 6] = s1; s_red[8 + (tid >> 6)] = s2; }
      __syncthreads();
      if (tid < 256) {
        float S1 = s_red[0] + s_red[1] + s_red[2] + s_red[3];
        float S2 = s_red[8] + s_red[9] + s_red[10] + s_red[11];
        float m = S1 * (1.f / 256), rs = rsqrtf(S2 * (1.f / 256) - m * m + 1e-6f);
        float v = (x - m) * rs * p2s_r + p2b_r;
        float vn = __shfl_xor(v, 1);
        if (!(tid & 1)) s_z16[tid >> 1] = pack2(v, vn);
      }
    }
    __syncthreads();

    // FFN1 slice + gelu
    mvr<64, 4, 16, 256>(wW1, s_z16, s_part, tid);
    __syncthreads();
    if (tid < 256) {
      float v = 0.f;
#pragma unroll
      for (int s = 0; s < 8; ++s) v += s_part[s * 256 + tid];
      float gl = gelu_f(v + b1_r);
      float vn = __shfl_xor(gl, 1);
      if (!(tid & 1)) s_h16[tid >> 1] = pack2(gl, vn);
    }
    __syncthreads();

    // FFN2 slice: half regs, half LDS
    {
      const int g = tid & 63, s = tid >> 6;
      float acc[4] = {0.f, 0.f, 0.f, 0.f};
#pragma unroll
      for (int jj = 0; jj < 8; ++jj) {
        u32 xp = s_h16[s * 16 + jj];
        acc[0] = dot2(xp, wW2r[jj * 4 + 0], acc[0]);
        acc[1] = dot2(xp, wW2r[jj * 4 + 1], acc[1]);
        acc[2] = dot2(xp, wW2r[jj * 4 + 2], acc[2]);
        acc[3] = dot2(xp, wW2r[jj * 4 + 3], acc[3]);
      }
#pragma unroll
      for (int jj = 0; jj < 8; ++jj) {
        u32 xp = s_h16[s * 16 + 8 + jj];
        const u32* wp = &s_w2[(s * 8 + jj) * 256 + g * 4];
        acc[0] = dot2(xp, wp[0], acc[0]);
        acc[1] = dot2(xp, wp[1], acc[1]);
        acc[2] = dot2(xp, wp[2], acc[2]);
        acc[3] = dot2(xp, wp[3], acc[3]);
      }
      float* pp = s_part + s * 256 + g * 4;
      pp[0] = acc[0]; pp[1] = acc[1]; pp[2] = acc[2]; pp[3] = acc[3];
    }
    __syncthreads();
    if (tid < 256) {
      float v = 0.f;
#pragma unroll
      for (int s = 0; s < 8; ++s) v += s_part[s * 256 + tid];
      if (j == 0) v += xm_r + b2_r;
      __hip_atomic_store(&pxo[(b * 4 + j) * 256 + tid], v, __ATOMIC_RELAXED, __HIP_MEMORY_SCOPE_AGENT);
    }
    __syncthreads();
    if (tid == 0) {
      __threadfence();
      __hip_atomic_store(&seqx[b * 4 + j], t + 1, __ATOMIC_RELEASE, __HIP_MEMORY_SCOPE_AGENT);
    }
    if (tid < 4) {
      while (__hip_atomic_load(&seqx[b * 4 + tid], __ATOMIC_ACQUIRE, __HIP_MEMORY_SCOPE_AGENT) < t + 1)
        __builtin_amdgcn_s_sleep(1);
    }
    __syncthreads();
    if (tid < 256) {
      float x0 = __hip_atomic_load(&pxo[(b * 4 + 0) * 256 + tid], __ATOMIC_RELAXED, __HIP_MEMORY_SCOPE_AGENT);
      float x1 = __hip_atomic_load(&pxo[(b * 4 + 1) * 256 + tid], __ATOMIC_RELAXED, __HIP_MEMORY_SCOPE_AGENT);
      float x2 = __hip_atomic_load(&pxo[(b * 4 + 2) * 256 + tid], __ATOMIC_RELAXED, __HIP_MEMORY_SCOPE_AGENT);
      float x3 = __hip_atomic_load(&pxo[(b * 4 + 3) * 256 + tid], __ATOMIC_RELAXED, __HIP_MEMORY_SCOPE_AGENT);
      float xo = (x0 + x1) + (x2 + x3);
      const int frz = (s_frz[t >> 2] >> ((t & 3) * 8)) & 0xff;
      if (!frz) ssum_r = ssum_r * l_r + xo * (1.f - l_r);
      if (j == 0) {
        float vn = __shfl_xor(xo, 1);
        if (!(tid & 1)) xog[((size_t)b * TT + t) * 128 + (tid >> 1)] = pack2(xo, vn);
      }
    }
    __syncthreads();
  }
}

// logits = xout(32768x256 f16) @ Wa(256x1024 f16) + ba, fp32 out
__global__ __launch_bounds__(256) void logits_kernel(
    const u16* __restrict__ xo, const u16* __restrict__ Wa,
    const float* __restrict__ ba, float* __restrict__ out) {
  __shared__ float AsT[64][68];
  __shared__ float Bs[64][68];
  const int r0 = blockIdx.x * 64;
  const int c0 = blockIdx.y * 64;
  const int tid = threadIdx.x;
  const int tx = tid & 15, ty = tid >> 4;
  float acc[4][4] = {};
  for (int k0 = 0; k0 < EE; k0 += 64) {
    __syncthreads();
    for (int l = tid * 4; l < 4096; l += 1024) {
      int rr = l >> 6, cc = l & 63;
      us4 av = *(const us4*)(xo + ((size_t)(r0 + rr)) * EE + k0 + cc);
      us4 wv = *(const us4*)(Wa + ((size_t)(k0 + rr)) * 1024 + c0 + cc);
#pragma unroll
      for (int jj = 0; jj < 4; ++jj) {
        AsT[cc + jj][rr] = h2f((u16)av[jj]);
        Bs[rr][cc + jj] = h2f((u16)wv[jj]);
      }
    }
    __syncthreads();
#pragma unroll 4
    for (int kk = 0; kk < 64; ++kk) {
      float4 a4 = *(const float4*)&AsT[kk][ty * 4];
      float4 b4 = *(const float4*)&Bs[kk][tx * 4];
      float av_[4] = {a4.x, a4.y, a4.z, a4.w};
      float bv_[4] = {b4.x, b4.y, b4.z, b4.w};
#pragma unroll
      for (int i = 0; i < 4; ++i)
#pragma unroll
        for (int jj = 0; jj < 4; ++jj) acc[i][jj] += av_[i] * bv_[jj];
    }
  }
  float bav[4];
#pragma unroll
  for (int jj = 0; jj < 4; ++jj) bav[jj] = ba[c0 + tx * 4 + jj];
#pragma unroll
  for (int i = 0; i < 4; ++i) {
    float4 v;
    v.x = acc[i][0] + bav[0];
    v.y = acc[i][1] + bav[1];
    v.z = acc[i][2] + bav[2];
    v.w = acc[i][3] + bav[3];
    *(float4*)(out + ((size_t)(r0 + ty * 4 + i)) * 1024 + c0 + tx * 4) = v;
  }
}

extern "C" void kernel_launch(void* const* d_in, const int* in_sizes, int n_in,
                              void* d_out, int out_size, void* d_ws, size_t ws_size,
                              hipStream_t stream) {
  const float* obs  = (const float*)d_in[0];
  const unsigned char* freeze = (const unsigned char*)d_in[1];
  const float* Wi   = (const float*)d_in[2];
  const float* bi   = (const float*)d_in[3];
  const float* temb = (const float*)d_in[4];
  const float* alpha = (const float*)d_in[5];
  const float* lam  = (const float*)d_in[6];
  const float* ln1s = (const float*)d_in[7];
  const float* ln1b = (const float*)d_in[8];
  const float* Wq   = (const float*)d_in[9];
  const float* bq   = (const float*)d_in[10];
  const float* Wk   = (const float*)d_in[11];
  const float* bk   = (const float*)d_in[12];
  const float* Wv   = (const float*)d_in[13];
  const float* bv   = (const float*)d_in[14];
  const float* Wo   = (const float*)d_in[15];
  const float* bo   = (const float*)d_in[16];
  const float* ln2s = (const float*)d_in[17];
  const float* ln2b = (const float*)d_in[18];
  const float* W1   = (const float*)d_in[19];
  const float* b1   = (const float*)d_in[20];
  const float* W2   = (const float*)d_in[21];
  const float* b2   = (const float*)d_in[22];
  const float* Wa   = (const float*)d_in[23];
  const float* ba   = (const float*)d_in[24];
  u16* ws = (u16*)d_ws;

  hipLaunchKernelGGL(convert_kernel, dim3((CONV_TOTAL + 255) / 256), dim3(256), 0, stream,
                     Wi, Wq, Wk, Wv, Wo, W1, W2, Wa, ws);
  hipLaunchKernelGGL(scan_kernel, dim3(BB * 4), dim3(NT), 0, stream,
                     obs, freeze, bi, temb, alpha, lam, ln1s, ln1b,
                     bq, bk, bv, bo, ln2s, ln2b, b1, b2, ws);
  hipLaunchKernelGGL(logits_kernel, dim3(BB * TT / 64, 1024 / 64), dim3(256), 0, stream,
                     ws + 2 * W_XO, ws + 2 * W_WA, ba, (float*)d_out);
}